// Round 1
// baseline (98.998 us; speedup 1.0000x reference)
//
#include <hip/hip_runtime.h>
#include <cstdint>

namespace {
constexpr int kGrid = 64;
constexpr int kG = kGrid * kGrid * kGrid;     // 262144 cells
constexpr int kC = 16;
constexpr int kB = 2;
constexpr int kN = 8192;
constexpr int kPts = kB * kN;                 // 16384 points
constexpr float kDX = 1.0f / 64.0f;
constexpr float kRad2 = 0.00152587890625f;    // (2.5/64)^2, exact
constexpr float kInvRad = 25.6f;              // not used for u (we divide), kept for ref
constexpr float kRad = 0.0390625f;            // 2.5/64, exact
constexpr float kEps = 1e-12f;
constexpr float kFourOverPi = 1.27323954473516268615f;

constexpr int PPB = 8;                        // points per block
constexpr int THREADS = PPB * 16;             // 128
constexpr int MAXREC = 96;                    // max valid neighbors is 81
constexpr int SLOT = 12;                      // floats per record (16B-aligned)
constexpr int GSTRIDE = MAXREC * SLOT + 4;    // 1156: skews groups across LDS banks
}

__device__ __forceinline__ float sgnf(float v) {
    return (v > 0.f) ? 1.f : ((v < 0.f) ? -1.f : 0.f);
}

// ---- transpose [B][C][G] -> [B][G][C] so per-cell channel gathers are one 64B line ----
__global__ __launch_bounds__(256) void transpose_feat_k(const float* __restrict__ in,
                                                        float* __restrict__ feat) {
    int idx = blockIdx.x * 256 + threadIdx.x;      // over B*G
    if (idx >= kB * kG) return;
    int b = idx >> 18;                              // /kG
    int g = idx & (kG - 1);
    float v[16];
#pragma unroll
    for (int c = 0; c < 16; ++c) v[c] = in[((size_t)(b * 16 + c)) * kG + g];
    float4* dst = reinterpret_cast<float4*>(feat + (size_t)idx * 16);
    dst[0] = make_float4(v[0], v[1], v[2], v[3]);
    dst[1] = make_float4(v[4], v[5], v[6], v[7]);
    dst[2] = make_float4(v[8], v[9], v[10], v[11]);
    dst[3] = make_float4(v[12], v[13], v[14], v[15]);
}

__global__ __launch_bounds__(THREADS) void cconv_main(
    const float* __restrict__ input, const float* __restrict__ pos,
    const float* __restrict__ W, const float* __restrict__ feat,
    float* __restrict__ out, int use_feat)
{
    __shared__ __align__(16) float rec[PPB * GSTRIDE];

    const int tid = threadIdx.x;
    const int lig = tid & 15;           // lane in 16-lane group == channel / out-channel
    const int grp = tid >> 4;           // point in block (0..7)
    const int lane = tid & 63;
    const int gsh = (lane >> 4) << 4;   // ballot shift for this group-in-wave
    const int pt = blockIdx.x * PPB + grp;
    const int b = pt / kN;

    const float px = pos[pt * 3 + 0];
    const float py = pos[pt * 3 + 1];
    const float pz = pos[pt * 3 + 2];
    const int bx = (int)floorf(px * 64.f);
    const int by = (int)floorf(py * 64.f);
    const int bz = (int)floorf(pz * 64.f);

    float* grec = rec + grp * GSTRIDE;
    int nv = 0;

    // ---- pass 1a: validity test over 216 candidates, ballot-compact (rel, flat) ----
    for (int it = 0; it < 14; ++it) {
        int k = it * 16 + lig;
        bool valid = false;
        float rx = 0.f, ry = 0.f, rz = 0.f;
        int flat = 0;
        if (k < 216) {
            int a = k / 36;
            int r = k - a * 36;
            int b1 = r / 6;
            int c1 = r - b1 * 6;
            int g0 = bx + a - 2, g1 = by + b1 - 2, g2 = bz + c1 - 2;
            bool inb = (g0 >= 0) & (g0 < 64) & (g1 >= 0) & (g1 < 64) &
                       (g2 >= 0) & (g2 < 64);
            int q0 = min(max(g0, 0), 63);
            int q1 = min(max(g1, 0), 63);
            int q2 = min(max(g2, 0), 63);
            flat = (q0 * 64 + q1) * 64 + q2;
            // grid_pos[i] == i*DX exactly (power-of-two scale) -> compute, don't load
            rx = __fsub_rn((float)q0 * kDX, px);
            ry = __fsub_rn((float)q1 * kDX, py);
            rz = __fsub_rn((float)q2 * kDX, pz);
            // forbid fma-contraction so the <= compare matches XLA mul-then-add
            float d2 = __fadd_rn(__fadd_rn(__fmul_rn(rx, rx), __fmul_rn(ry, ry)),
                                 __fmul_rn(rz, rz));
            valid = inb && (d2 <= kRad2);
        }
        unsigned long long ball = __ballot(valid);
        unsigned bits = (unsigned)((ball >> gsh) & 0xFFFFull);
        if (valid) {
            int slot = nv + __popc(bits & ((1u << lig) - 1u));
            float* rp = grec + slot * SLOT;
            *reinterpret_cast<float4*>(rp) =
                make_float4(rx, ry, rz, __int_as_float(flat));
        }
        nv += __popc(bits);
    }
    __syncthreads();

    // ---- pass 1b: heavy mapping (sphere->cylinder->cube + hat weights), dense lanes ----
    for (int it = 0; it < 6; ++it) {
        int s = it * 16 + lig;
        if (s < nv) {
            float* rp = grec + s * SLOT;
            float4 rc = *reinterpret_cast<const float4*>(rp);
            int flat = __float_as_int(rc.w);
            float ux = rc.x / kRad, uy = rc.y / kRad, uz = rc.z / kRad;

            // sphere -> cylinder
            float sq = ux * ux + uy * uy + uz * uz;
            float nrm = sqrtf(fmaxf(sq, kEps));
            float xy2 = ux * ux + uy * uy;
            float xc, yc, zc;
            if (1.25f * uz * uz > xy2) {
                float s2 = sqrtf(3.f * nrm / (nrm + fabsf(uz) + kEps));
                xc = ux * s2; yc = uy * s2; zc = sgnf(uz) * nrm;
            } else {
                float s2 = nrm / sqrtf(fmaxf(xy2, kEps));
                xc = ux * s2; yc = uy * s2; zc = 1.5f * uz;
            }
            if (sq <= kEps) { xc = 0.f; yc = 0.f; zc = 0.f; }

            // cylinder -> cube
            float xy2b = xc * xc + yc * yc;
            float nxy = sqrtf(fmaxf(xy2b, kEps));
            float xo, yo;
            if (fabsf(yc) <= fabsf(xc)) {
                float sx = (fabsf(xc) > kEps) ? xc : 1.f;
                float tx = sgnf(xc) * nxy;
                xo = tx;
                yo = tx * kFourOverPi * atanf(yc / sx);
            } else {
                float sy = (fabsf(yc) > kEps) ? yc : 1.f;
                float ty = sgnf(yc) * nxy;
                xo = ty * kFourOverPi * atanf(xc / sy);
                yo = ty;
            }
            if (xy2b <= kEps) { xo = 0.f; yo = 0.f; }
            float zo = zc;

            // hat weights per axis: c = clip((v*0.5+0.5)*2, 0, 2); w = max(0, 1-|c-tap|)
            float cx = fminf(fmaxf((xo * 0.5f + 0.5f) * 2.0f, 0.f), 2.f);
            float cy = fminf(fmaxf((yo * 0.5f + 0.5f) * 2.0f, 0.f), 2.f);
            float cz = fminf(fmaxf((zo * 0.5f + 0.5f) * 2.0f, 0.f), 2.f);
            float wx0 = fmaxf(0.f, 1.f - fabsf(cx));
            float wx1 = fmaxf(0.f, 1.f - fabsf(cx - 1.f));
            float wx2 = fmaxf(0.f, 1.f - fabsf(cx - 2.f));
            float wy0 = fmaxf(0.f, 1.f - fabsf(cy));
            float wy1 = fmaxf(0.f, 1.f - fabsf(cy - 1.f));
            float wy2 = fmaxf(0.f, 1.f - fabsf(cy - 2.f));
            float wz0 = fmaxf(0.f, 1.f - fabsf(cz));
            float wz1 = fmaxf(0.f, 1.f - fabsf(cz - 1.f));
            float wz2 = fmaxf(0.f, 1.f - fabsf(cz - 2.f));

            *reinterpret_cast<float4*>(rp)     = make_float4(wx0, wx1, wx2, wy0);
            *reinterpret_cast<float4*>(rp + 4) = make_float4(wy1, wy2, wz0, wz1);
            *reinterpret_cast<float2*>(rp + 8) = make_float2(wz2, __int_as_float(flat));
        }
    }
    __syncthreads();

    // ---- pass 2: per-lane channel c = lig, accumulate acc[27] over valid neighbors ----
    float acc[27];
#pragma unroll
    for (int t = 0; t < 27; ++t) acc[t] = 0.f;

    const float* fb = use_feat ? (feat + (size_t)b * kG * 16)
                               : (input + (size_t)b * 16 * kG);
    for (int s = 0; s < nv; ++s) {
        const float* rp = grec + s * SLOT;
        float4 A  = *reinterpret_cast<const float4*>(rp);      // wx0 wx1 wx2 wy0
        float4 Bv = *reinterpret_cast<const float4*>(rp + 4);  // wy1 wy2 wz0 wz1
        float2 Cv = *reinterpret_cast<const float2*>(rp + 8);  // wz2 flat
        int flat = __float_as_int(Cv.y);
        float f = use_feat ? fb[flat * 16 + lig] : fb[lig * kG + flat];
        float m0 = Bv.z * f, m1 = Bv.w * f, m2 = Cv.x * f;
        float p;
        p = A.x * A.w;  acc[0]  += p * m0; acc[1]  += p * m1; acc[2]  += p * m2;
        p = A.x * Bv.x; acc[3]  += p * m0; acc[4]  += p * m1; acc[5]  += p * m2;
        p = A.x * Bv.y; acc[6]  += p * m0; acc[7]  += p * m1; acc[8]  += p * m2;
        p = A.y * A.w;  acc[9]  += p * m0; acc[10] += p * m1; acc[11] += p * m2;
        p = A.y * Bv.x; acc[12] += p * m0; acc[13] += p * m1; acc[14] += p * m2;
        p = A.y * Bv.y; acc[15] += p * m0; acc[16] += p * m1; acc[17] += p * m2;
        p = A.z * A.w;  acc[18] += p * m0; acc[19] += p * m1; acc[20] += p * m2;
        p = A.z * Bv.x; acc[21] += p * m0; acc[22] += p * m1; acc[23] += p * m2;
        p = A.z * Bv.y; acc[24] += p * m0; acc[25] += p * m1; acc[26] += p * m2;
    }

    // ---- pass 3: out[d] = sum_{t,c} acc_c[t] * W[t][c][d] / max(count,1) ----
    float partial[16];
#pragma unroll
    for (int d = 0; d < 16; ++d) partial[d] = 0.f;
#pragma unroll
    for (int t = 0; t < 27; ++t) {
        const float4* wr = reinterpret_cast<const float4*>(W + t * 256 + lig * 16);
        float4 a0 = wr[0], a1 = wr[1], a2 = wr[2], a3 = wr[3];
        float at = acc[t];
        partial[0]  += at * a0.x; partial[1]  += at * a0.y;
        partial[2]  += at * a0.z; partial[3]  += at * a0.w;
        partial[4]  += at * a1.x; partial[5]  += at * a1.y;
        partial[6]  += at * a1.z; partial[7]  += at * a1.w;
        partial[8]  += at * a2.x; partial[9]  += at * a2.y;
        partial[10] += at * a2.z; partial[11] += at * a2.w;
        partial[12] += at * a3.x; partial[13] += at * a3.y;
        partial[14] += at * a3.z; partial[15] += at * a3.w;
    }
#pragma unroll
    for (int m = 1; m < 16; m <<= 1) {
#pragma unroll
        for (int d = 0; d < 16; ++d)
            partial[d] += __shfl_xor(partial[d], m, 16);
    }
    float res = 0.f;
#pragma unroll
    for (int d = 0; d < 16; ++d)
        if (lig == d) res = partial[d];
    res = res / fmaxf((float)nv, 1.f);
    out[(size_t)pt * 16 + lig] = res;
}

extern "C" void kernel_launch(void* const* d_in, const int* in_sizes, int n_in,
                              void* d_out, int out_size, void* d_ws, size_t ws_size,
                              hipStream_t stream) {
    const float* input = (const float*)d_in[0];   // [2,16,64,64,64]
    const float* pos   = (const float*)d_in[1];   // [2,8192,3]
    const float* W     = (const float*)d_in[2];   // [3,3,3,16,16]
    // d_in[3] grid_pos unused: grid_pos[i] == i*DX exactly
    float* out  = (float*)d_out;
    float* feat = (float*)d_ws;

    const size_t feat_bytes = (size_t)kB * kG * 16 * sizeof(float);
    int use_feat = (d_ws != nullptr && ws_size >= feat_bytes) ? 1 : 0;

    if (use_feat) {
        transpose_feat_k<<<(kB * kG + 255) / 256, 256, 0, stream>>>(input, feat);
    }
    cconv_main<<<kPts / PPB, THREADS, 0, stream>>>(input, pos, W, feat, out, use_feat);
}

// Round 2
// 75.781 us; speedup vs baseline: 1.3064x; 1.3064x over previous
//
#include <hip/hip_runtime.h>
#include <cstdint>

namespace {
constexpr int kGrid = 64;
constexpr int kG = kGrid * kGrid * kGrid;     // 262144 cells
constexpr int kB = 2;
constexpr int kN = 8192;
constexpr int kPts = kB * kN;                 // 16384 points
constexpr float kDX = 1.0f / 64.0f;
constexpr float kRad2 = 0.00152587890625f;    // (2.5/64)^2, exact
constexpr float kRad = 0.0390625f;            // 2.5/64, exact
constexpr float kEps = 1e-12f;
constexpr float kFourOverPi = 1.27323954473516268615f;

constexpr int PPB = 4;                        // points per block (1 wave each)
constexpr int THREADS = PPB * 64;             // 256
constexpr int MAXREC = 96;                    // max valid neighbors is 81
constexpr int SLOT = 12;                      // floats per record (16B-aligned)
constexpr int GSTRIDE = MAXREC * SLOT + 4;    // 1156 floats per point
}

__device__ __forceinline__ float sgnf(float v) {
    return (v > 0.f) ? 1.f : ((v < 0.f) ? -1.f : 0.f);
}

// ---- transpose [B][C][G] -> [B][G][C] so per-cell channel gathers are one 64B line ----
__global__ __launch_bounds__(256) void transpose_feat_k(const float* __restrict__ in,
                                                        float* __restrict__ feat) {
    int idx = blockIdx.x * 256 + threadIdx.x;      // over B*G
    if (idx >= kB * kG) return;
    int b = idx >> 18;                              // /kG
    int g = idx & (kG - 1);
    float v[16];
#pragma unroll
    for (int c = 0; c < 16; ++c) v[c] = in[((size_t)(b * 16 + c)) * kG + g];
    float4* dst = reinterpret_cast<float4*>(feat + (size_t)idx * 16);
    dst[0] = make_float4(v[0], v[1], v[2], v[3]);
    dst[1] = make_float4(v[4], v[5], v[6], v[7]);
    dst[2] = make_float4(v[8], v[9], v[10], v[11]);
    dst[3] = make_float4(v[12], v[13], v[14], v[15]);
}

__global__ __launch_bounds__(THREADS) void cconv_main(
    const float* __restrict__ input, const float* __restrict__ pos,
    const float* __restrict__ W, const float* __restrict__ feat,
    float* __restrict__ out, int use_feat)
{
    __shared__ __align__(16) float rec[PPB * GSTRIDE];

    const int tid = threadIdx.x;
    const int wv = tid >> 6;            // point-in-block (one wave per point)
    const int lane = tid & 63;
    const int sg = lane >> 4;           // sub-group 0..3
    const int lig = lane & 15;          // channel lane within sub-group
    const int pt = blockIdx.x * PPB + wv;
    const int b = pt >> 13;             // / kN

    const float px = pos[pt * 3 + 0];
    const float py = pos[pt * 3 + 1];
    const float pz = pos[pt * 3 + 2];
    const int bx = (int)floorf(px * 64.f);
    const int by = (int)floorf(py * 64.f);
    const int bz = (int)floorf(pz * 64.f);

    float* grec = rec + wv * GSTRIDE;
    int nv = 0;

    // ---- pass 1a: validity test over 216 candidates, full-wave ballot-compact ----
#pragma unroll
    for (int it = 0; it < 4; ++it) {
        int k = it * 64 + lane;
        bool valid = false;
        float rx = 0.f, ry = 0.f, rz = 0.f;
        int flat = 0;
        if (k < 216) {
            int a = k / 36;
            int r = k - a * 36;
            int b1 = r / 6;
            int c1 = r - b1 * 6;
            int g0 = bx + a - 2, g1 = by + b1 - 2, g2 = bz + c1 - 2;
            bool inb = (g0 >= 0) & (g0 < 64) & (g1 >= 0) & (g1 < 64) &
                       (g2 >= 0) & (g2 < 64);
            int q0 = min(max(g0, 0), 63);
            int q1 = min(max(g1, 0), 63);
            int q2 = min(max(g2, 0), 63);
            flat = (q0 * 64 + q1) * 64 + q2;
            // grid_pos[i] == i*DX exactly (power-of-two scale) -> compute, don't load
            rx = __fsub_rn((float)q0 * kDX, px);
            ry = __fsub_rn((float)q1 * kDX, py);
            rz = __fsub_rn((float)q2 * kDX, pz);
            // forbid fma-contraction so the <= compare matches XLA mul-then-add
            float d2 = __fadd_rn(__fadd_rn(__fmul_rn(rx, rx), __fmul_rn(ry, ry)),
                                 __fmul_rn(rz, rz));
            valid = inb && (d2 <= kRad2);
        }
        unsigned long long ball = __ballot(valid);
        if (valid) {
            int slot = nv + __popcll(ball & ((1ull << lane) - 1ull));
            float* rp = grec + slot * SLOT;
            *reinterpret_cast<float4*>(rp) =
                make_float4(rx, ry, rz, __int_as_float(flat));
        }
        nv += (int)__popcll(ball);
    }
    __syncthreads();

    // ---- pass 1b: heavy mapping (sphere->cylinder->cube + hat weights), dense lanes ----
    for (int s0 = 0; s0 < nv; s0 += 64) {
        int s = s0 + lane;
        if (s < nv) {
            float* rp = grec + s * SLOT;
            float4 rc = *reinterpret_cast<const float4*>(rp);
            int flat = __float_as_int(rc.w);
            float ux = rc.x / kRad, uy = rc.y / kRad, uz = rc.z / kRad;

            // sphere -> cylinder
            float sq = ux * ux + uy * uy + uz * uz;
            float nrm = sqrtf(fmaxf(sq, kEps));
            float xy2 = ux * ux + uy * uy;
            float xc, yc, zc;
            if (1.25f * uz * uz > xy2) {
                float s2 = sqrtf(3.f * nrm / (nrm + fabsf(uz) + kEps));
                xc = ux * s2; yc = uy * s2; zc = sgnf(uz) * nrm;
            } else {
                float s2 = nrm / sqrtf(fmaxf(xy2, kEps));
                xc = ux * s2; yc = uy * s2; zc = 1.5f * uz;
            }
            if (sq <= kEps) { xc = 0.f; yc = 0.f; zc = 0.f; }

            // cylinder -> cube
            float xy2b = xc * xc + yc * yc;
            float nxy = sqrtf(fmaxf(xy2b, kEps));
            float xo, yo;
            if (fabsf(yc) <= fabsf(xc)) {
                float sx = (fabsf(xc) > kEps) ? xc : 1.f;
                float tx = sgnf(xc) * nxy;
                xo = tx;
                yo = tx * kFourOverPi * atanf(yc / sx);
            } else {
                float sy = (fabsf(yc) > kEps) ? yc : 1.f;
                float ty = sgnf(yc) * nxy;
                xo = ty * kFourOverPi * atanf(xc / sy);
                yo = ty;
            }
            if (xy2b <= kEps) { xo = 0.f; yo = 0.f; }
            float zo = zc;

            // hat weights per axis: c = clip((v*0.5+0.5)*2, 0, 2); w = max(0, 1-|c-tap|)
            float cx = fminf(fmaxf((xo * 0.5f + 0.5f) * 2.0f, 0.f), 2.f);
            float cy = fminf(fmaxf((yo * 0.5f + 0.5f) * 2.0f, 0.f), 2.f);
            float cz = fminf(fmaxf((zo * 0.5f + 0.5f) * 2.0f, 0.f), 2.f);
            float wx0 = fmaxf(0.f, 1.f - fabsf(cx));
            float wx1 = fmaxf(0.f, 1.f - fabsf(cx - 1.f));
            float wx2 = fmaxf(0.f, 1.f - fabsf(cx - 2.f));
            float wy0 = fmaxf(0.f, 1.f - fabsf(cy));
            float wy1 = fmaxf(0.f, 1.f - fabsf(cy - 1.f));
            float wy2 = fmaxf(0.f, 1.f - fabsf(cy - 2.f));
            float wz0 = fmaxf(0.f, 1.f - fabsf(cz));
            float wz1 = fmaxf(0.f, 1.f - fabsf(cz - 1.f));
            float wz2 = fmaxf(0.f, 1.f - fabsf(cz - 2.f));

            *reinterpret_cast<float4*>(rp)     = make_float4(wx0, wx1, wx2, wy0);
            *reinterpret_cast<float4*>(rp + 4) = make_float4(wy1, wy2, wz0, wz1);
            *reinterpret_cast<float2*>(rp + 8) = make_float2(wz2, __int_as_float(flat));
        }
    }
    __syncthreads();

    // ---- pass 2: sub-group sg takes records s = sg, sg+4, ...; lane channel = lig ----
    float acc[27];
#pragma unroll
    for (int t = 0; t < 27; ++t) acc[t] = 0.f;

    const float* fb = use_feat ? (feat + (size_t)b * kG * 16)
                               : (input + (size_t)b * 16 * kG);

    int s = sg;
    float4 A, Bv; float2 Cv; float f = 0.f;
    if (s < nv) {
        const float* rp = grec + s * SLOT;
        A  = *reinterpret_cast<const float4*>(rp);
        Bv = *reinterpret_cast<const float4*>(rp + 4);
        Cv = *reinterpret_cast<const float2*>(rp + 8);
        int flat = __float_as_int(Cv.y);
        f = use_feat ? fb[(size_t)flat * 16 + lig] : fb[(size_t)lig * kG + flat];
    }
    while (s < nv) {
        // prefetch next record + feature (one gather in flight during FMAs)
        int s2 = s + 4;
        float4 An, Bn; float2 Cn; float fn = 0.f;
        if (s2 < nv) {
            const float* rp = grec + s2 * SLOT;
            An = *reinterpret_cast<const float4*>(rp);
            Bn = *reinterpret_cast<const float4*>(rp + 4);
            Cn = *reinterpret_cast<const float2*>(rp + 8);
            int flat = __float_as_int(Cn.y);
            fn = use_feat ? fb[(size_t)flat * 16 + lig] : fb[(size_t)lig * kG + flat];
        }
        float m0 = Bv.z * f, m1 = Bv.w * f, m2 = Cv.x * f;
        float p;
        p = A.x * A.w;  acc[0]  += p * m0; acc[1]  += p * m1; acc[2]  += p * m2;
        p = A.x * Bv.x; acc[3]  += p * m0; acc[4]  += p * m1; acc[5]  += p * m2;
        p = A.x * Bv.y; acc[6]  += p * m0; acc[7]  += p * m1; acc[8]  += p * m2;
        p = A.y * A.w;  acc[9]  += p * m0; acc[10] += p * m1; acc[11] += p * m2;
        p = A.y * Bv.x; acc[12] += p * m0; acc[13] += p * m1; acc[14] += p * m2;
        p = A.y * Bv.y; acc[15] += p * m0; acc[16] += p * m1; acc[17] += p * m2;
        p = A.z * A.w;  acc[18] += p * m0; acc[19] += p * m1; acc[20] += p * m2;
        p = A.z * Bv.x; acc[21] += p * m0; acc[22] += p * m1; acc[23] += p * m2;
        p = A.z * Bv.y; acc[24] += p * m0; acc[25] += p * m1; acc[26] += p * m2;
        A = An; Bv = Bn; Cv = Cn; f = fn; s = s2;
    }

    // reduce partial acc across the 4 sub-groups -> every lane has full acc
#pragma unroll
    for (int t = 0; t < 27; ++t) {
        acc[t] += __shfl_xor(acc[t], 16);
        acc[t] += __shfl_xor(acc[t], 32);
    }

    // ---- pass 3: split taps across sub-groups; out[d] = sum_{t,c} acc_c[t]*W[t][c][d] ----
    float partial[16];
#pragma unroll
    for (int d = 0; d < 16; ++d) partial[d] = 0.f;
    for (int t = sg; t < 27; t += 4) {
        const float4* wr = reinterpret_cast<const float4*>(W + t * 256 + lig * 16);
        float4 a0 = wr[0], a1 = wr[1], a2 = wr[2], a3 = wr[3];
        float at = acc[t];
        partial[0]  += at * a0.x; partial[1]  += at * a0.y;
        partial[2]  += at * a0.z; partial[3]  += at * a0.w;
        partial[4]  += at * a1.x; partial[5]  += at * a1.y;
        partial[6]  += at * a1.z; partial[7]  += at * a1.w;
        partial[8]  += at * a2.x; partial[9]  += at * a2.y;
        partial[10] += at * a2.z; partial[11] += at * a2.w;
        partial[12] += at * a3.x; partial[13] += at * a3.y;
        partial[14] += at * a3.z; partial[15] += at * a3.w;
    }
#pragma unroll
    for (int m = 1; m < 16; m <<= 1) {
#pragma unroll
        for (int d = 0; d < 16; ++d)
            partial[d] += __shfl_xor(partial[d], m, 16);
    }
    float res = 0.f;
#pragma unroll
    for (int d = 0; d < 16; ++d)
        if (lig == d) res = partial[d];
    // sum sub-group contributions
    res += __shfl_xor(res, 16);
    res += __shfl_xor(res, 32);
    res = res / fmaxf((float)nv, 1.f);
    if (lane < 16) out[(size_t)pt * 16 + lig] = res;
}

extern "C" void kernel_launch(void* const* d_in, const int* in_sizes, int n_in,
                              void* d_out, int out_size, void* d_ws, size_t ws_size,
                              hipStream_t stream) {
    const float* input = (const float*)d_in[0];   // [2,16,64,64,64]
    const float* pos   = (const float*)d_in[1];   // [2,8192,3]
    const float* W     = (const float*)d_in[2];   // [3,3,3,16,16]
    // d_in[3] grid_pos unused: grid_pos[i] == i*DX exactly
    float* out  = (float*)d_out;
    float* feat = (float*)d_ws;

    const size_t feat_bytes = (size_t)kB * kG * 16 * sizeof(float);
    int use_feat = (d_ws != nullptr && ws_size >= feat_bytes) ? 1 : 0;

    if (use_feat) {
        transpose_feat_k<<<(kB * kG + 255) / 256, 256, 0, stream>>>(input, feat);
    }
    cconv_main<<<kPts / PPB, THREADS, 0, stream>>>(input, pos, W, feat, out, use_feat);
}